// Round 4
// baseline (12749.310 us; speedup 1.0000x reference)
//
#include <hip/hip_runtime.h>
#include <hip/hip_bf16.h>
#include <math.h>

#define S 1024
#define B 4
#define Dm 768
#define NH 12
#define DH 64
#define NL 4
#define DI 3072

typedef __hip_bfloat16 bf16;

__device__ __forceinline__ float b2f(bf16 x) { return __bfloat162float(x); }
__device__ __forceinline__ bf16 f2b(float x) { return __float2bfloat16(x); }

__device__ __forceinline__ float ldv(const float* p, size_t i) { return p[i]; }
__device__ __forceinline__ float ldv(const bf16* p, size_t i) { return b2f(p[i]); }
__device__ __forceinline__ void stv(float* p, size_t i, float v) { p[i] = v; }
__device__ __forceinline__ void stv(bf16* p, size_t i, float v) { p[i] = f2b(v); }

__device__ __forceinline__ float wave_sum(float x) {
  #pragma unroll
  for (int off = 32; off > 0; off >>= 1) x += __shfl_xor(x, off, 64);
  return x;
}

// h[s,b,d] = word_emb[inp[s,b], d] * sqrt(D) + pos_emb(s, d)   (h fp32, in d_out)
__global__ void embed_kernel(const int* __restrict__ inp, const float* __restrict__ wemb,
                             float* __restrict__ h) {
  int idx = blockIdx.x * blockDim.x + threadIdx.x;
  if (idx >= S * B * Dm) return;
  int d = idx % Dm;
  int sb = idx / Dm;
  int b = sb % B;
  int s = sb / B;
  int tok = inp[s * B + b];
  float e = wemb[(size_t)tok * Dm + d] * 27.712812921102035f; // sqrt(768)
  float ps = (float)(S - 1 - s);
  float pe;
  if (d < Dm / 2) {
    float invf = expf(-(2.0f * (float)d / (float)Dm) * 9.210340371976184f); // ln(10000)
    pe = sinf(ps * invf);
  } else {
    int j = d - Dm / 2;
    float invf = expf(-(2.0f * (float)j / (float)Dm) * 9.210340371976184f);
    pe = cosf(ps * invf);
  }
  h[idx] = e + pe;
}

// C[M,N] = A[M,K] @ W[N,K]^T (+bias)(+relu). M=4096 via grid.y=64. fp32 acc, bf16 out.
template <typename TA>
__global__ void gemm_kernel(const TA* __restrict__ A, const float* __restrict__ W,
                            const float* __restrict__ bias, bf16* __restrict__ C,
                            int N, int K, int relu) {
  __shared__ float As[64][17];
  __shared__ float Ws[64][17];
  int t = threadIdx.x;           // 256
  int tx = t & 15, ty = t >> 4;
  int m0 = blockIdx.y * 64, n0 = blockIdx.x * 64;
  float acc[4][4] = {};
  for (int k0 = 0; k0 < K; k0 += 16) {
    #pragma unroll
    for (int i2 = 0; i2 < 4; i2++) {
      int idx = t + i2 * 256;          // 0..1023
      int r = idx >> 4, c = idx & 15;
      As[r][c] = ldv(A, (size_t)(m0 + r) * K + k0 + c);
      Ws[r][c] = W[(size_t)(n0 + r) * K + k0 + c];
    }
    __syncthreads();
    #pragma unroll
    for (int kk = 0; kk < 16; kk++) {
      float av[4], wv[4];
      #pragma unroll
      for (int i = 0; i < 4; i++) av[i] = As[ty * 4 + i][kk];
      #pragma unroll
      for (int j = 0; j < 4; j++) wv[j] = Ws[tx * 4 + j][kk];
      #pragma unroll
      for (int i = 0; i < 4; i++)
        #pragma unroll
        for (int j = 0; j < 4; j++)
          acc[i][j] += av[i] * wv[j];
    }
    __syncthreads();
  }
  #pragma unroll
  for (int j = 0; j < 4; j++) {
    float bv = bias ? bias[n0 + tx * 4 + j] : 0.0f;
    #pragma unroll
    for (int i = 0; i < 4; i++) {
      float r2 = acc[i][j] + bv;
      if (relu) r2 = fmaxf(r2, 0.0f);
      C[(size_t)(m0 + ty * 4 + i) * N + n0 + tx * 4 + j] = f2b(r2);
    }
  }
}

// causal attention, one wave per (i,b,n) row, online softmax
__global__ void attn_kernel(const bf16* __restrict__ q, const bf16* __restrict__ k,
                            const bf16* __restrict__ v, bf16* __restrict__ att) {
  int wid = threadIdx.x >> 6;
  int lane = threadIdx.x & 63;
  int row = blockIdx.x * 4 + wid;      // ((i*B)+b)*NH+n
  int n = row % NH;
  int sb = row / NH;
  int b = sb % B;
  int i = sb / B;
  int base_i = (i * B + b) * Dm + n * DH;
  float qd = b2f(q[base_i + lane]) * 0.125f;   // 1/sqrt(DH)
  float m = -INFINITY, lsum = 0.0f, acc = 0.0f;
  for (int j = 0; j <= i; j++) {
    int bj = (j * B + b) * Dm + n * DH;
    float kd = b2f(k[bj + lane]);
    float s = wave_sum(qd * kd);
    float mn = fmaxf(m, s);
    float c = __expf(m - mn);
    float e = __expf(s - mn);
    lsum = lsum * c + e;
    acc = acc * c + e * b2f(v[bj + lane]);
    m = mn;
  }
  att[base_i + lane] = f2b(acc / lsum);
}

// content retrieval + gated combine, and vd = k - delta (uses cK = elu(v)+1 !)
__global__ void meminfer_kernel(const bf16* __restrict__ q, const bf16* __restrict__ k,
                                const bf16* __restrict__ v,
                                const float* __restrict__ mem, const float* __restrict__ mnorm,
                                bf16* __restrict__ att, bf16* __restrict__ vd) {
  int wid = threadIdx.x >> 6;
  int lane = threadIdx.x & 63;
  int row = blockIdx.x * 4 + wid;      // ((s*B)+b)*NH+n
  int n = row % NH;
  int sb = row / NH;
  int b = sb % B;
  int s = sb / B;
  int base = (s * B + b) * Dm + n * DH;
  float qv = b2f(q[base + lane]);
  float vv = b2f(v[base + lane]);
  float kv = b2f(k[base + lane]);
  float cq = qv > 0.0f ? qv + 1.0f : expf(qv);   // elu+1
  float ck = vv > 0.0f ? vv + 1.0f : expf(vv);
  float nr = mnorm[(size_t)(b * NH + n) * DH + lane];
  float denq = wave_sum(cq * nr);
  float denk = wave_sum(ck * nr);
  const float* mrow = mem + (size_t)(b * NH + n) * DH * DH;
  float numq = 0.0f, numk = 0.0f;
  #pragma unroll 8
  for (int kk = 0; kk < DH; kk++) {
    float mval = mrow[(size_t)kk * DH + lane];
    numq += __shfl(cq, kk, 64) * mval;
    numk += __shfl(ck, kk, 64) * mval;
  }
  float gate = 1.0f / (1.0f + expf(-0.01f));
  float content = numq / denq;
  float delta = numk / denk;
  att[base + lane] = f2b(gate * content + (1.0f - gate) * b2f(att[base + lane]));
  vd[base + lane] = f2b(kv - delta);
}

// new_mem[b,n,k,v] = mem + sum_s cK[s,k]*vd[s,v];  new_norm[b,n,k] = norm + sum_s cK[s,k]
__global__ void memupd_kernel(const bf16* __restrict__ v, const bf16* __restrict__ vd,
                              const float* __restrict__ mem, const float* __restrict__ mnorm,
                              float* __restrict__ out_mem, float* __restrict__ out_norm) {
  int b = blockIdx.x / NH, n = blockIdx.x % NH;
  int t = threadIdx.x;        // 256
  int k = t >> 2;             // 0..63
  int v0 = (t & 3) * 16;      // 0,16,32,48
  __shared__ float ckl[8][DH];
  __shared__ float vdl[8][DH];
  float acc[16];
  #pragma unroll
  for (int j = 0; j < 16; j++) acc[j] = 0.0f;
  float nsum = 0.0f;
  for (int s0 = 0; s0 < S; s0 += 8) {
    #pragma unroll
    for (int i2 = 0; i2 < 2; i2++) {
      int idx = t + i2 * 256;        // 0..511
      int sp = idx >> 6, dd = idx & 63;
      int g = ((s0 + sp) * B + b) * Dm + n * DH + dd;
      float vv = b2f(v[g]);
      ckl[sp][dd] = vv > 0.0f ? vv + 1.0f : expf(vv);
      vdl[sp][dd] = b2f(vd[g]);
    }
    __syncthreads();
    #pragma unroll
    for (int sp = 0; sp < 8; sp++) {
      float c = ckl[sp][k];
      if ((t & 3) == 0) nsum += c;
      #pragma unroll
      for (int j = 0; j < 16; j++) acc[j] += c * vdl[sp][v0 + j];
    }
    __syncthreads();
  }
  const float* mrow = mem + (size_t)(b * NH + n) * DH * DH;
  float* orow = out_mem + (size_t)(b * NH + n) * DH * DH;
  #pragma unroll
  for (int j = 0; j < 16; j++) {
    int idx = k * DH + v0 + j;
    orow[idx] = mrow[idx] + acc[j];
  }
  if ((t & 3) == 0) {
    int idx = (b * NH + n) * DH + k;
    out_norm[idx] = mnorm[idx] + nsum;
  }
}

// out = layer_norm(x + y, g, b); one block per row of 768
template <typename TX, typename TY, typename TO>
__global__ void addln_kernel(const TX* __restrict__ x, const TY* __restrict__ y,
                             const float* __restrict__ g, const float* __restrict__ bb,
                             TO* __restrict__ out) {
  int row = blockIdx.x;
  int t = threadIdx.x;      // 256
  float vals[3];
  float sum = 0.0f, sq = 0.0f;
  #pragma unroll
  for (int i = 0; i < 3; i++) {
    size_t idx = (size_t)row * Dm + t + i * 256;
    float vv = ldv(x, idx) + ldv(y, idx);
    vals[i] = vv;
    sum += vv;
    sq += vv * vv;
  }
  sum = wave_sum(sum);
  sq = wave_sum(sq);
  __shared__ float s1[4], s2[4];
  int w = t >> 6, lane = t & 63;
  if (lane == 0) { s1[w] = sum; s2[w] = sq; }
  __syncthreads();
  if (t == 0) {
    s1[0] = s1[0] + s1[1] + s1[2] + s1[3];
    s2[0] = s2[0] + s2[1] + s2[2] + s2[3];
  }
  __syncthreads();
  sum = s1[0]; sq = s2[0];
  float mu = sum / 768.0f;
  float var = sq / 768.0f - mu * mu;
  float rs = rsqrtf(var + 1e-5f);
  #pragma unroll
  for (int i = 0; i < 3; i++) {
    int d = t + i * 256;
    stv(out, (size_t)row * Dm + d, (vals[i] - mu) * rs * g[d] + bb[d]);
  }
}

extern "C" void kernel_launch(void* const* d_in, const int* in_sizes, int n_in,
                              void* d_out, int out_size, void* d_ws, size_t ws_size,
                              hipStream_t stream) {
  (void)in_sizes; (void)n_in; (void)out_size; (void)ws_size;
  const int*   inp   = (const int*)d_in[0];
  const float* wemb  = (const float*)d_in[1];
  const float* Wq    = (const float*)d_in[2];
  const float* Wkv   = (const float*)d_in[3];
  const float* Wo    = (const float*)d_in[4];
  const float* ln1g  = (const float*)d_in[5];
  const float* ln1b  = (const float*)d_in[6];
  const float* fW1   = (const float*)d_in[7];
  const float* fb1   = (const float*)d_in[8];
  const float* fW2   = (const float*)d_in[9];
  const float* fb2   = (const float*)d_in[10];
  const float* ln2g  = (const float*)d_in[11];
  const float* ln2b  = (const float*)d_in[12];
  const float* mem   = (const float*)d_in[13];
  const float* mnorm = (const float*)d_in[14];

  const size_t SBD = (size_t)S * B * Dm;   // 3,145,728

  bf16* ws   = (bf16*)d_ws;
  bf16* q    = ws;              // slot 0
  bf16* kbuf = ws + SBD;        // slot 1
  bf16* vbuf = ws + 2 * SBD;    // slot 2
  bf16* vd   = ws + 3 * SBD;    // slot 3
  bf16* att  = ws + 4 * SBD;    // slot 4
  bf16* out1 = ws + 5 * SBD;    // slot 5
  bf16* ffm  = q;               // 4*SBD: aliases slots 0-3 (dead by FF1)
  bf16* tmp  = q;               // Wo-GEMM out (q dead after meminfer)
  bf16* ff2o = att;             // FF2 out (att dead after Wo-GEMM)

  float* h    = (float*)d_out;  // residual stream lives in d_out (fp32)
  float* outm = h + SBD;
  float* outn = outm + (size_t)NL * B * NH * DH * DH;

  dim3 b256(256);
  embed_kernel<<<dim3((S * B * Dm + 255) / 256), b256, 0, stream>>>(inp, wemb, h);

  for (int l = 0; l < NL; l++) {
    const float* Wq_l  = Wq + (size_t)l * Dm * Dm;
    const float* Wk_l  = Wkv + (size_t)l * 2 * Dm * Dm;      // rows 0..D-1  -> k
    const float* Wv_l  = Wk_l + (size_t)Dm * Dm;             // rows D..2D-1 -> v
    const float* Wo_l  = Wo + (size_t)l * Dm * Dm;
    const float* mem_l = mem + (size_t)l * B * NH * DH * DH;
    const float* mn_l  = mnorm + (size_t)l * B * NH * DH;

    gemm_kernel<<<dim3(Dm / 64, 64), b256, 0, stream>>>(h, Wq_l, (const float*)nullptr, q, Dm, Dm, 0);
    gemm_kernel<<<dim3(Dm / 64, 64), b256, 0, stream>>>(h, Wk_l, (const float*)nullptr, kbuf, Dm, Dm, 0);
    gemm_kernel<<<dim3(Dm / 64, 64), b256, 0, stream>>>(h, Wv_l, (const float*)nullptr, vbuf, Dm, Dm, 0);

    attn_kernel<<<dim3(S * B * NH / 4), b256, 0, stream>>>(q, kbuf, vbuf, att);
    meminfer_kernel<<<dim3(S * B * NH / 4), b256, 0, stream>>>(q, kbuf, vbuf, mem_l, mn_l,
                                                               att, vd);
    memupd_kernel<<<dim3(B * NH), b256, 0, stream>>>(vbuf, vd, mem_l, mn_l,
        outm + (size_t)l * B * NH * DH * DH, outn + (size_t)l * B * NH * DH);

    gemm_kernel<<<dim3(Dm / 64, 64), b256, 0, stream>>>(att, Wo_l, (const float*)nullptr, tmp, Dm, Dm, 0);
    addln_kernel<<<dim3(S * B), b256, 0, stream>>>(h, tmp, ln1g + l * Dm, ln1b + l * Dm, out1);

    gemm_kernel<<<dim3(DI / 64, 64), b256, 0, stream>>>(out1, fW1 + (size_t)l * DI * Dm,
                                                        fb1 + l * DI, ffm, DI, Dm, 1);
    gemm_kernel<<<dim3(Dm / 64, 64), b256, 0, stream>>>(ffm, fW2 + (size_t)l * Dm * DI,
                                                        fb2 + l * Dm, ff2o, Dm, DI, 0);
    addln_kernel<<<dim3(S * B), b256, 0, stream>>>(out1, ff2o, ln2g + l * Dm, ln2b + l * Dm, h);
  }
}

// Round 5
// 6357.396 us; speedup vs baseline: 2.0054x; 2.0054x over previous
//
#include <hip/hip_runtime.h>
#include <hip/hip_bf16.h>
#include <math.h>

#define S 1024
#define B 4
#define Dm 768
#define NH 12
#define DH 64
#define NL 4
#define DI 3072

typedef __hip_bfloat16 bf16;
typedef short bf16x8 __attribute__((ext_vector_type(8)));
typedef float f32x4 __attribute__((ext_vector_type(4)));

__device__ __forceinline__ float b2f(bf16 x) { return __bfloat162float(x); }
__device__ __forceinline__ bf16 f2b(float x) { return __float2bfloat16(x); }

__device__ __forceinline__ float ldv(const float* p, size_t i) { return p[i]; }
__device__ __forceinline__ float ldv(const bf16* p, size_t i) { return b2f(p[i]); }
__device__ __forceinline__ void stv(float* p, size_t i, float v) { p[i] = v; }
__device__ __forceinline__ void stv(bf16* p, size_t i, float v) { p[i] = f2b(v); }

__device__ __forceinline__ float wave_sum(float x) {
  #pragma unroll
  for (int off = 32; off > 0; off >>= 1) x += __shfl_xor(x, off, 64);
  return x;
}

// h[s,b,d] = word_emb[inp[s,b], d] * sqrt(D) + pos_emb(s, d)   (h fp32, in d_out)
__global__ void embed_kernel(const int* __restrict__ inp, const float* __restrict__ wemb,
                             float* __restrict__ h) {
  int idx = blockIdx.x * blockDim.x + threadIdx.x;
  if (idx >= S * B * Dm) return;
  int d = idx % Dm;
  int sb = idx / Dm;
  int b = sb % B;
  int s = sb / B;
  int tok = inp[s * B + b];
  float e = wemb[(size_t)tok * Dm + d] * 27.712812921102035f; // sqrt(768)
  float ps = (float)(S - 1 - s);
  float pe;
  if (d < Dm / 2) {
    float invf = expf(-(2.0f * (float)d / (float)Dm) * 9.210340371976184f); // ln(10000)
    pe = sinf(ps * invf);
  } else {
    int j = d - Dm / 2;
    float invf = expf(-(2.0f * (float)j / (float)Dm) * 9.210340371976184f);
    pe = cosf(ps * invf);
  }
  h[idx] = e + pe;
}

// C[M,N] = A[M,K] @ W[N,K]^T (+bias)(+relu). M=4096 via grid.y=64. fp32 acc, bf16 out.
template <typename TA>
__global__ void gemm_kernel(const TA* __restrict__ A, const float* __restrict__ W,
                            const float* __restrict__ bias, bf16* __restrict__ C,
                            int N, int K, int relu) {
  __shared__ float As[64][17];
  __shared__ float Ws[64][17];
  int t = threadIdx.x;           // 256
  int tx = t & 15, ty = t >> 4;
  int m0 = blockIdx.y * 64, n0 = blockIdx.x * 64;
  float acc[4][4] = {};
  for (int k0 = 0; k0 < K; k0 += 16) {
    #pragma unroll
    for (int i2 = 0; i2 < 4; i2++) {
      int idx = t + i2 * 256;          // 0..1023
      int r = idx >> 4, c = idx & 15;
      As[r][c] = ldv(A, (size_t)(m0 + r) * K + k0 + c);
      Ws[r][c] = W[(size_t)(n0 + r) * K + k0 + c];
    }
    __syncthreads();
    #pragma unroll
    for (int kk = 0; kk < 16; kk++) {
      float av[4], wv[4];
      #pragma unroll
      for (int i = 0; i < 4; i++) av[i] = As[ty * 4 + i][kk];
      #pragma unroll
      for (int j = 0; j < 4; j++) wv[j] = Ws[tx * 4 + j][kk];
      #pragma unroll
      for (int i = 0; i < 4; i++)
        #pragma unroll
        for (int j = 0; j < 4; j++)
          acc[i][j] += av[i] * wv[j];
    }
    __syncthreads();
  }
  #pragma unroll
  for (int j = 0; j < 4; j++) {
    float bv = bias ? bias[n0 + tx * 4 + j] : 0.0f;
    #pragma unroll
    for (int i = 0; i < 4; i++) {
      float r2 = acc[i][j] + bv;
      if (relu) r2 = fmaxf(r2, 0.0f);
      C[(size_t)(m0 + ty * 4 + i) * N + n0 + tx * 4 + j] = f2b(r2);
    }
  }
}

// Flash attention with MFMA. Block = 256 thr = 4 waves; one 64-row Q tile per (b,n).
// Wave w owns 16 q-rows. S=Q K^T via mfma 16x16x32 bf16, online softmax in C-layout,
// P -> A-layout via per-wave LDS round trip, O += P V with V staged transposed.
__global__ __launch_bounds__(256) void attn_flash(const bf16* __restrict__ q,
                                                  const bf16* __restrict__ k,
                                                  const bf16* __restrict__ v,
                                                  bf16* __restrict__ att) {
  const int it = blockIdx.x;       // q-tile index (16)
  const int bn = blockIdx.y;       // b*NH+n (48)
  const int b = bn / NH, n = bn % NH;
  const int t = threadIdx.x;
  const int w = t >> 6, lane = t & 63;
  const int col = lane & 15, quad = lane >> 4;
  const int i0 = it * 64;

  __shared__ __align__(16) unsigned short Kt[64 * 72];  // K[j][d], row stride 72
  __shared__ __align__(16) unsigned short Vt[64 * 72];  // V^T[d][j]
  __shared__ __align__(16) unsigned short Pw[64 * 72];  // per-wave P rows [w*16..w*16+15]

  const unsigned short* qp = (const unsigned short*)q;
  const unsigned short* kp = (const unsigned short*)k;
  const unsigned short* vp = (const unsigned short*)v;

  // Q A-frags: m = col (q-row within wave tile), k-dim = quad*8 + 0..7 (+32 for ks=1)
  bf16x8 aq[2];
  {
    size_t qb = ((size_t)(i0 + w * 16 + col) * B + b) * Dm + n * DH + quad * 8;
    aq[0] = *(const bf16x8*)(qp + qb);
    aq[1] = *(const bf16x8*)(qp + qb + 32);
  }

  const f32x4 zf = {0.0f, 0.0f, 0.0f, 0.0f};
  float mrow[4], lrow[4];
  f32x4 o[4];
  #pragma unroll
  for (int r = 0; r < 4; r++) { mrow[r] = -1e30f; lrow[r] = 0.0f; }
  #pragma unroll
  for (int db = 0; db < 4; db++) o[db] = zf;

  const int jj = t >> 2;           // 0..63 (staging row)
  const int d0 = (t & 3) << 4;     // 0,16,32,48

  for (int jt = 0; jt <= it; jt++) {
    const int j0 = jt * 64;
    __syncthreads();               // previous tile's Kt/Vt reads done
    {
      size_t gb = ((size_t)(j0 + jj) * B + b) * Dm + n * DH + d0;
      *(uint4*)&Kt[jj * 72 + d0] = *(const uint4*)(kp + gb);
      *(uint4*)&Kt[jj * 72 + d0 + 8] = *(const uint4*)(kp + gb + 8);
      unsigned short tv[16];
      *(uint4*)tv = *(const uint4*)(vp + gb);
      *(uint4*)(tv + 8) = *(const uint4*)(vp + gb + 8);
      #pragma unroll
      for (int x = 0; x < 16; x++) Vt[(d0 + x) * 72 + jj] = tv[x];
    }
    __syncthreads();

    // S = Q K^T  (per wave: 16 rows x 64 cols as 4 n-blocks)
    f32x4 sf[4];
    #pragma unroll
    for (int nb = 0; nb < 4; nb++) sf[nb] = zf;
    #pragma unroll
    for (int ks = 0; ks < 2; ks++) {
      #pragma unroll
      for (int nb = 0; nb < 4; nb++) {
        bf16x8 kb = *(const bf16x8*)&Kt[(nb * 16 + col) * 72 + ks * 32 + quad * 8];
        sf[nb] = __builtin_amdgcn_mfma_f32_16x16x32_bf16(aq[ks], kb, sf[nb], 0, 0, 0);
      }
    }

    const bool diag = (jt == it);
    #pragma unroll
    for (int r = 0; r < 4; r++) {
      const int irow = i0 + w * 16 + quad * 4 + r;
      float sv[4];
      #pragma unroll
      for (int nb = 0; nb < 4; nb++) {
        float s = sf[nb][r] * 0.125f;    // 1/sqrt(DH)
        if (diag && (j0 + nb * 16 + col) > irow) s = -1e30f;
        sv[nb] = s;
      }
      float rm = fmaxf(fmaxf(sv[0], sv[1]), fmaxf(sv[2], sv[3]));
      #pragma unroll
      for (int off = 8; off > 0; off >>= 1) rm = fmaxf(rm, __shfl_xor(rm, off, 64));
      const float mn = fmaxf(mrow[r], rm);
      const float alpha = __expf(mrow[r] - mn);
      mrow[r] = mn;
      float ps = 0.0f;
      #pragma unroll
      for (int nb = 0; nb < 4; nb++) {
        float p = __expf(sv[nb] - mn);
        ps += p;
        bf16 hb = f2b(p);
        Pw[(w * 16 + quad * 4 + r) * 72 + nb * 16 + col] = *(unsigned short*)&hb;
      }
      #pragma unroll
      for (int off = 8; off > 0; off >>= 1) ps += __shfl_xor(ps, off, 64);
      lrow[r] = lrow[r] * alpha + ps;
      #pragma unroll
      for (int db = 0; db < 4; db++) o[db][r] *= alpha;
    }

    // O += P V  (P from per-wave LDS region in A-layout; V^T as B operand)
    #pragma unroll
    for (int ks = 0; ks < 2; ks++) {
      bf16x8 pa = *(const bf16x8*)&Pw[(w * 16 + col) * 72 + ks * 32 + quad * 8];
      #pragma unroll
      for (int db = 0; db < 4; db++) {
        bf16x8 vb = *(const bf16x8*)&Vt[(db * 16 + col) * 72 + ks * 32 + quad * 8];
        o[db] = __builtin_amdgcn_mfma_f32_16x16x32_bf16(pa, vb, o[db], 0, 0, 0);
      }
    }
  }

  unsigned short* ap = (unsigned short*)att;
  #pragma unroll
  for (int r = 0; r < 4; r++) {
    const int irow = i0 + w * 16 + quad * 4 + r;
    const float inv = 1.0f / lrow[r];
    size_t ob = ((size_t)irow * B + b) * Dm + n * DH + col;
    #pragma unroll
    for (int db = 0; db < 4; db++) {
      bf16 hb = f2b(o[db][r] * inv);
      ap[ob + db * 16] = *(unsigned short*)&hb;
    }
  }
}

// content retrieval + gated combine, and vd = k - delta (uses cK = elu(v)+1 !)
__global__ void meminfer_kernel(const bf16* __restrict__ q, const bf16* __restrict__ k,
                                const bf16* __restrict__ v,
                                const float* __restrict__ mem, const float* __restrict__ mnorm,
                                bf16* __restrict__ att, bf16* __restrict__ vd) {
  int wid = threadIdx.x >> 6;
  int lane = threadIdx.x & 63;
  int row = blockIdx.x * 4 + wid;      // ((s*B)+b)*NH+n
  int n = row % NH;
  int sb = row / NH;
  int b = sb % B;
  int s = sb / B;
  int base = (s * B + b) * Dm + n * DH;
  float qv = b2f(q[base + lane]);
  float vv = b2f(v[base + lane]);
  float kv = b2f(k[base + lane]);
  float cq = qv > 0.0f ? qv + 1.0f : expf(qv);   // elu+1
  float ck = vv > 0.0f ? vv + 1.0f : expf(vv);
  float nr = mnorm[(size_t)(b * NH + n) * DH + lane];
  float denq = wave_sum(cq * nr);
  float denk = wave_sum(ck * nr);
  const float* mrow = mem + (size_t)(b * NH + n) * DH * DH;
  float numq = 0.0f, numk = 0.0f;
  #pragma unroll 8
  for (int kk = 0; kk < DH; kk++) {
    float mval = mrow[(size_t)kk * DH + lane];
    numq += __shfl(cq, kk, 64) * mval;
    numk += __shfl(ck, kk, 64) * mval;
  }
  float gate = 1.0f / (1.0f + expf(-0.01f));
  float content = numq / denq;
  float delta = numk / denk;
  att[base + lane] = f2b(gate * content + (1.0f - gate) * b2f(att[base + lane]));
  vd[base + lane] = f2b(kv - delta);
}

// new_mem[b,n,k,v] = mem + sum_s cK[s,k]*vd[s,v];  new_norm[b,n,k] = norm + sum_s cK[s,k]
__global__ void memupd_kernel(const bf16* __restrict__ v, const bf16* __restrict__ vd,
                              const float* __restrict__ mem, const float* __restrict__ mnorm,
                              float* __restrict__ out_mem, float* __restrict__ out_norm) {
  int b = blockIdx.x / NH, n = blockIdx.x % NH;
  int t = threadIdx.x;        // 256
  int k = t >> 2;             // 0..63
  int v0 = (t & 3) * 16;      // 0,16,32,48
  __shared__ float ckl[8][DH];
  __shared__ float vdl[8][DH];
  float acc[16];
  #pragma unroll
  for (int j = 0; j < 16; j++) acc[j] = 0.0f;
  float nsum = 0.0f;
  for (int s0 = 0; s0 < S; s0 += 8) {
    #pragma unroll
    for (int i2 = 0; i2 < 2; i2++) {
      int idx = t + i2 * 256;        // 0..511
      int sp = idx >> 6, dd = idx & 63;
      int g = ((s0 + sp) * B + b) * Dm + n * DH + dd;
      float vv = b2f(v[g]);
      ckl[sp][dd] = vv > 0.0f ? vv + 1.0f : expf(vv);
      vdl[sp][dd] = b2f(vd[g]);
    }
    __syncthreads();
    #pragma unroll
    for (int sp = 0; sp < 8; sp++) {
      float c = ckl[sp][k];
      if ((t & 3) == 0) nsum += c;
      #pragma unroll
      for (int j = 0; j < 16; j++) acc[j] += c * vdl[sp][v0 + j];
    }
    __syncthreads();
  }
  const float* mrow = mem + (size_t)(b * NH + n) * DH * DH;
  float* orow = out_mem + (size_t)(b * NH + n) * DH * DH;
  #pragma unroll
  for (int j = 0; j < 16; j++) {
    int idx = k * DH + v0 + j;
    orow[idx] = mrow[idx] + acc[j];
  }
  if ((t & 3) == 0) {
    int idx = (b * NH + n) * DH + k;
    out_norm[idx] = mnorm[idx] + nsum;
  }
}

// out = layer_norm(x + y, g, b); one block per row of 768
template <typename TX, typename TY, typename TO>
__global__ void addln_kernel(const TX* __restrict__ x, const TY* __restrict__ y,
                             const float* __restrict__ g, const float* __restrict__ bb,
                             TO* __restrict__ out) {
  int row = blockIdx.x;
  int t = threadIdx.x;      // 256
  float vals[3];
  float sum = 0.0f, sq = 0.0f;
  #pragma unroll
  for (int i = 0; i < 3; i++) {
    size_t idx = (size_t)row * Dm + t + i * 256;
    float vv = ldv(x, idx) + ldv(y, idx);
    vals[i] = vv;
    sum += vv;
    sq += vv * vv;
  }
  sum = wave_sum(sum);
  sq = wave_sum(sq);
  __shared__ float s1[4], s2[4];
  int w = t >> 6, lane = t & 63;
  if (lane == 0) { s1[w] = sum; s2[w] = sq; }
  __syncthreads();
  if (t == 0) {
    s1[0] = s1[0] + s1[1] + s1[2] + s1[3];
    s2[0] = s2[0] + s2[1] + s2[2] + s2[3];
  }
  __syncthreads();
  sum = s1[0]; sq = s2[0];
  float mu = sum / 768.0f;
  float var = sq / 768.0f - mu * mu;
  float rs = rsqrtf(var + 1e-5f);
  #pragma unroll
  for (int i = 0; i < 3; i++) {
    int d = t + i * 256;
    stv(out, (size_t)row * Dm + d, (vals[i] - mu) * rs * g[d] + bb[d]);
  }
}

extern "C" void kernel_launch(void* const* d_in, const int* in_sizes, int n_in,
                              void* d_out, int out_size, void* d_ws, size_t ws_size,
                              hipStream_t stream) {
  (void)in_sizes; (void)n_in; (void)out_size; (void)ws_size;
  const int*   inp   = (const int*)d_in[0];
  const float* wemb  = (const float*)d_in[1];
  const float* Wq    = (const float*)d_in[2];
  const float* Wkv   = (const float*)d_in[3];
  const float* Wo    = (const float*)d_in[4];
  const float* ln1g  = (const float*)d_in[5];
  const float* ln1b  = (const float*)d_in[6];
  const float* fW1   = (const float*)d_in[7];
  const float* fb1   = (const float*)d_in[8];
  const float* fW2   = (const float*)d_in[9];
  const float* fb2   = (const float*)d_in[10];
  const float* ln2g  = (const float*)d_in[11];
  const float* ln2b  = (const float*)d_in[12];
  const float* mem   = (const float*)d_in[13];
  const float* mnorm = (const float*)d_in[14];

  const size_t SBD = (size_t)S * B * Dm;   // 3,145,728

  bf16* ws   = (bf16*)d_ws;
  bf16* q    = ws;              // slot 0
  bf16* kbuf = ws + SBD;        // slot 1
  bf16* vbuf = ws + 2 * SBD;    // slot 2
  bf16* vd   = ws + 3 * SBD;    // slot 3
  bf16* att  = ws + 4 * SBD;    // slot 4
  bf16* out1 = ws + 5 * SBD;    // slot 5
  bf16* ffm  = q;               // 4*SBD: aliases slots 0-3 (dead by FF1)
  bf16* tmp  = q;               // Wo-GEMM out (q dead after meminfer)
  bf16* ff2o = att;             // FF2 out (att dead after Wo-GEMM)

  float* h    = (float*)d_out;  // residual stream lives in d_out (fp32)
  float* outm = h + SBD;
  float* outn = outm + (size_t)NL * B * NH * DH * DH;

  dim3 b256(256);
  embed_kernel<<<dim3((S * B * Dm + 255) / 256), b256, 0, stream>>>(inp, wemb, h);

  for (int l = 0; l < NL; l++) {
    const float* Wq_l  = Wq + (size_t)l * Dm * Dm;
    const float* Wk_l  = Wkv + (size_t)l * 2 * Dm * Dm;      // rows 0..D-1  -> k
    const float* Wv_l  = Wk_l + (size_t)Dm * Dm;             // rows D..2D-1 -> v
    const float* Wo_l  = Wo + (size_t)l * Dm * Dm;
    const float* mem_l = mem + (size_t)l * B * NH * DH * DH;
    const float* mn_l  = mnorm + (size_t)l * B * NH * DH;

    gemm_kernel<<<dim3(Dm / 64, 64), b256, 0, stream>>>(h, Wq_l, (const float*)nullptr, q, Dm, Dm, 0);
    gemm_kernel<<<dim3(Dm / 64, 64), b256, 0, stream>>>(h, Wk_l, (const float*)nullptr, kbuf, Dm, Dm, 0);
    gemm_kernel<<<dim3(Dm / 64, 64), b256, 0, stream>>>(h, Wv_l, (const float*)nullptr, vbuf, Dm, Dm, 0);

    attn_flash<<<dim3(S / 64, B * NH), b256, 0, stream>>>(q, kbuf, vbuf, att);
    meminfer_kernel<<<dim3(S * B * NH / 4), b256, 0, stream>>>(q, kbuf, vbuf, mem_l, mn_l,
                                                               att, vd);
    memupd_kernel<<<dim3(B * NH), b256, 0, stream>>>(vbuf, vd, mem_l, mn_l,
        outm + (size_t)l * B * NH * DH * DH, outn + (size_t)l * B * NH * DH);

    gemm_kernel<<<dim3(Dm / 64, 64), b256, 0, stream>>>(att, Wo_l, (const float*)nullptr, tmp, Dm, Dm, 0);
    addln_kernel<<<dim3(S * B), b256, 0, stream>>>(h, tmp, ln1g + l * Dm, ln1b + l * Dm, out1);

    gemm_kernel<<<dim3(DI / 64, 64), b256, 0, stream>>>(out1, fW1 + (size_t)l * DI * Dm,
                                                        fb1 + l * DI, ffm, DI, Dm, 1);
    gemm_kernel<<<dim3(Dm / 64, 64), b256, 0, stream>>>(ffm, fW2 + (size_t)l * Dm * DI,
                                                        fb2 + l * Dm, ff2o, Dm, DI, 0);
    addln_kernel<<<dim3(S * B), b256, 0, stream>>>(out1, ff2o, ln2g + l * Dm, ln2b + l * Dm, h);
  }
}

// Round 6
// 2441.598 us; speedup vs baseline: 5.2217x; 2.6038x over previous
//
#include <hip/hip_runtime.h>
#include <hip/hip_bf16.h>
#include <math.h>

#define S 1024
#define B 4
#define Dm 768
#define NH 12
#define DH 64
#define NL 4
#define DI 3072

typedef __hip_bfloat16 bf16;
typedef short bf16x8 __attribute__((ext_vector_type(8)));
typedef float f32x4 __attribute__((ext_vector_type(4)));

__device__ __forceinline__ float b2f(bf16 x) { return __bfloat162float(x); }
__device__ __forceinline__ bf16 f2b(float x) { return __float2bfloat16(x); }

__device__ __forceinline__ float ldv(const float* p, size_t i) { return p[i]; }
__device__ __forceinline__ float ldv(const bf16* p, size_t i) { return b2f(p[i]); }
__device__ __forceinline__ void stv(float* p, size_t i, float v) { p[i] = v; }
__device__ __forceinline__ void stv(bf16* p, size_t i, float v) { p[i] = f2b(v); }

__device__ __forceinline__ float wave_sum(float x) {
  #pragma unroll
  for (int off = 32; off > 0; off >>= 1) x += __shfl_xor(x, off, 64);
  return x;
}

// load 16 source elements as bf16 bit patterns into d[16]
__device__ __forceinline__ void load16(const float* p, unsigned short* d) {
  #pragma unroll
  for (int i = 0; i < 4; i++) {
    float4 f = *(const float4*)(p + i * 4);
    bf16 b0 = f2b(f.x), b1 = f2b(f.y), b2 = f2b(f.z), b3 = f2b(f.w);
    d[i * 4 + 0] = *(unsigned short*)&b0;
    d[i * 4 + 1] = *(unsigned short*)&b1;
    d[i * 4 + 2] = *(unsigned short*)&b2;
    d[i * 4 + 3] = *(unsigned short*)&b3;
  }
}
__device__ __forceinline__ void load16(const bf16* p, unsigned short* d) {
  *(uint4*)d = *(const uint4*)p;
  *(uint4*)(d + 8) = *(const uint4*)(p + 8);
}

// h[s,b,d] = word_emb[inp[s,b], d] * sqrt(D) + pos_emb(s, d)   (h fp32, in d_out)
__global__ void embed_kernel(const int* __restrict__ inp, const float* __restrict__ wemb,
                             float* __restrict__ h) {
  int idx = blockIdx.x * blockDim.x + threadIdx.x;
  if (idx >= S * B * Dm) return;
  int d = idx % Dm;
  int sb = idx / Dm;
  int b = sb % B;
  int s = sb / B;
  int tok = inp[s * B + b];
  float e = wemb[(size_t)tok * Dm + d] * 27.712812921102035f; // sqrt(768)
  float ps = (float)(S - 1 - s);
  float pe;
  if (d < Dm / 2) {
    float invf = expf(-(2.0f * (float)d / (float)Dm) * 9.210340371976184f); // ln(10000)
    pe = sinf(ps * invf);
  } else {
    int j = d - Dm / 2;
    float invf = expf(-(2.0f * (float)j / (float)Dm) * 9.210340371976184f);
    pe = cosf(ps * invf);
  }
  h[idx] = e + pe;
}

// C[M,N] = A[M,K] @ W[N,K]^T (+bias)(+relu). MFMA bf16, fp32 acc, bf16 out.
// Block 256 thr = 4 waves (2x2); tile 128x128; BK=32; wave does 64x64 = 4x4 mfma tiles.
// LDS tiles stored in MFMA-fragment order: tile mt (16 rows x 32 k) occupies 512
// elems at mt*512; addr(m,k) = mt*512 + (k>>3)*128 + (m&15)*8 + (k&7).
template <typename TA>
__global__ __launch_bounds__(256) void gemm_mfma(const TA* __restrict__ A,
                                                 const float* __restrict__ W,
                                                 const float* __restrict__ bias,
                                                 bf16* __restrict__ C,
                                                 int N, int K, int relu) {
  __shared__ __align__(16) unsigned short Asm[128 * 32];
  __shared__ __align__(16) unsigned short Bsm[128 * 32];
  const int t = threadIdx.x;
  const int w = t >> 6, lane = t & 63;
  const int col = lane & 15, quad = lane >> 4;
  const int wm = w >> 1, wn = w & 1;
  const int m0 = blockIdx.y * 128, n0 = blockIdx.x * 128;
  const int sr = t >> 1;            // staging row 0..127
  const int sk = (t & 1) * 16;      // staging k offset 0/16
  const int sbase = (sr >> 4) * 512 + (sk >> 3) * 128 + (sr & 15) * 8;

  const f32x4 zf = {0.0f, 0.0f, 0.0f, 0.0f};
  f32x4 acc[4][4];
  #pragma unroll
  for (int mt = 0; mt < 4; mt++)
    #pragma unroll
    for (int nt = 0; nt < 4; nt++) acc[mt][nt] = zf;

  for (int kk = 0; kk < K; kk += 32) {
    unsigned short ta[16], tb[16];
    load16(A + (size_t)(m0 + sr) * K + kk + sk, ta);
    load16(W + (size_t)(n0 + sr) * K + kk + sk, tb);
    __syncthreads();                // prior iteration's frag reads done
    *(bf16x8*)&Asm[sbase] = *(bf16x8*)ta;
    *(bf16x8*)&Asm[sbase + 128] = *(bf16x8*)(ta + 8);
    *(bf16x8*)&Bsm[sbase] = *(bf16x8*)tb;
    *(bf16x8*)&Bsm[sbase + 128] = *(bf16x8*)(tb + 8);
    __syncthreads();
    bf16x8 af[4], bf[4];
    #pragma unroll
    for (int mt = 0; mt < 4; mt++)
      af[mt] = *(const bf16x8*)&Asm[(wm * 4 + mt) * 512 + quad * 128 + col * 8];
    #pragma unroll
    for (int nt = 0; nt < 4; nt++)
      bf[nt] = *(const bf16x8*)&Bsm[(wn * 4 + nt) * 512 + quad * 128 + col * 8];
    #pragma unroll
    for (int mt = 0; mt < 4; mt++)
      #pragma unroll
      for (int nt = 0; nt < 4; nt++)
        acc[mt][nt] = __builtin_amdgcn_mfma_f32_16x16x32_bf16(af[mt], bf[nt],
                                                              acc[mt][nt], 0, 0, 0);
  }

  #pragma unroll
  for (int nt = 0; nt < 4; nt++) {
    const int colg = n0 + wn * 64 + nt * 16 + col;
    const float bv = bias ? bias[colg] : 0.0f;
    #pragma unroll
    for (int mt = 0; mt < 4; mt++) {
      #pragma unroll
      for (int r = 0; r < 4; r++) {
        const int row = m0 + wm * 64 + mt * 16 + quad * 4 + r;
        float val = acc[mt][nt][r] + bv;
        if (relu) val = fmaxf(val, 0.0f);
        C[(size_t)row * N + colg] = f2b(val);
      }
    }
  }
}

// Flash attention with MFMA. Block = 256 thr = 4 waves; one 64-row Q tile per (b,n).
__global__ __launch_bounds__(256) void attn_flash(const bf16* __restrict__ q,
                                                  const bf16* __restrict__ k,
                                                  const bf16* __restrict__ v,
                                                  bf16* __restrict__ att) {
  const int it = blockIdx.x;       // q-tile index (16)
  const int bn = blockIdx.y;       // b*NH+n (48)
  const int b = bn / NH, n = bn % NH;
  const int t = threadIdx.x;
  const int w = t >> 6, lane = t & 63;
  const int col = lane & 15, quad = lane >> 4;
  const int i0 = it * 64;

  __shared__ __align__(16) unsigned short Kt[64 * 72];  // K[j][d], row stride 72
  __shared__ __align__(16) unsigned short Vt[64 * 72];  // V^T[d][j]
  __shared__ __align__(16) unsigned short Pw[64 * 72];  // per-wave P rows

  const unsigned short* qp = (const unsigned short*)q;
  const unsigned short* kp = (const unsigned short*)k;
  const unsigned short* vp = (const unsigned short*)v;

  bf16x8 aq[2];
  {
    size_t qb = ((size_t)(i0 + w * 16 + col) * B + b) * Dm + n * DH + quad * 8;
    aq[0] = *(const bf16x8*)(qp + qb);
    aq[1] = *(const bf16x8*)(qp + qb + 32);
  }

  const f32x4 zf = {0.0f, 0.0f, 0.0f, 0.0f};
  float mrow[4], lrow[4];
  f32x4 o[4];
  #pragma unroll
  for (int r = 0; r < 4; r++) { mrow[r] = -1e30f; lrow[r] = 0.0f; }
  #pragma unroll
  for (int db = 0; db < 4; db++) o[db] = zf;

  const int jj = t >> 2;           // 0..63 (staging row)
  const int d0 = (t & 3) << 4;     // 0,16,32,48

  for (int jt = 0; jt <= it; jt++) {
    const int j0 = jt * 64;
    __syncthreads();
    {
      size_t gb = ((size_t)(j0 + jj) * B + b) * Dm + n * DH + d0;
      *(uint4*)&Kt[jj * 72 + d0] = *(const uint4*)(kp + gb);
      *(uint4*)&Kt[jj * 72 + d0 + 8] = *(const uint4*)(kp + gb + 8);
      unsigned short tv[16];
      *(uint4*)tv = *(const uint4*)(vp + gb);
      *(uint4*)(tv + 8) = *(const uint4*)(vp + gb + 8);
      #pragma unroll
      for (int x = 0; x < 16; x++) Vt[(d0 + x) * 72 + jj] = tv[x];
    }
    __syncthreads();

    f32x4 sf[4];
    #pragma unroll
    for (int nb = 0; nb < 4; nb++) sf[nb] = zf;
    #pragma unroll
    for (int ks = 0; ks < 2; ks++) {
      #pragma unroll
      for (int nb = 0; nb < 4; nb++) {
        bf16x8 kb = *(const bf16x8*)&Kt[(nb * 16 + col) * 72 + ks * 32 + quad * 8];
        sf[nb] = __builtin_amdgcn_mfma_f32_16x16x32_bf16(aq[ks], kb, sf[nb], 0, 0, 0);
      }
    }

    const bool diag = (jt == it);
    #pragma unroll
    for (int r = 0; r < 4; r++) {
      const int irow = i0 + w * 16 + quad * 4 + r;
      float sv[4];
      #pragma unroll
      for (int nb = 0; nb < 4; nb++) {
        float s = sf[nb][r] * 0.125f;
        if (diag && (j0 + nb * 16 + col) > irow) s = -1e30f;
        sv[nb] = s;
      }
      float rm = fmaxf(fmaxf(sv[0], sv[1]), fmaxf(sv[2], sv[3]));
      #pragma unroll
      for (int off = 8; off > 0; off >>= 1) rm = fmaxf(rm, __shfl_xor(rm, off, 64));
      const float mn = fmaxf(mrow[r], rm);
      const float alpha = __expf(mrow[r] - mn);
      mrow[r] = mn;
      float ps = 0.0f;
      #pragma unroll
      for (int nb = 0; nb < 4; nb++) {
        float p = __expf(sv[nb] - mn);
        ps += p;
        bf16 hb = f2b(p);
        Pw[(w * 16 + quad * 4 + r) * 72 + nb * 16 + col] = *(unsigned short*)&hb;
      }
      #pragma unroll
      for (int off = 8; off > 0; off >>= 1) ps += __shfl_xor(ps, off, 64);
      lrow[r] = lrow[r] * alpha + ps;
      #pragma unroll
      for (int db = 0; db < 4; db++) o[db][r] *= alpha;
    }

    #pragma unroll
    for (int ks = 0; ks < 2; ks++) {
      bf16x8 pa = *(const bf16x8*)&Pw[(w * 16 + col) * 72 + ks * 32 + quad * 8];
      #pragma unroll
      for (int db = 0; db < 4; db++) {
        bf16x8 vb = *(const bf16x8*)&Vt[(db * 16 + col) * 72 + ks * 32 + quad * 8];
        o[db] = __builtin_amdgcn_mfma_f32_16x16x32_bf16(pa, vb, o[db], 0, 0, 0);
      }
    }
  }

  unsigned short* ap = (unsigned short*)att;
  #pragma unroll
  for (int r = 0; r < 4; r++) {
    const int irow = i0 + w * 16 + quad * 4 + r;
    const float inv = 1.0f / lrow[r];
    size_t ob = ((size_t)irow * B + b) * Dm + n * DH + col;
    #pragma unroll
    for (int db = 0; db < 4; db++) {
      bf16 hb = f2b(o[db][r] * inv);
      ap[ob + db * 16] = *(unsigned short*)&hb;
    }
  }
}

// content retrieval + gated combine, and vd = k - delta (uses cK = elu(v)+1 !)
__global__ void meminfer_kernel(const bf16* __restrict__ q, const bf16* __restrict__ k,
                                const bf16* __restrict__ v,
                                const float* __restrict__ mem, const float* __restrict__ mnorm,
                                bf16* __restrict__ att, bf16* __restrict__ vd) {
  int wid = threadIdx.x >> 6;
  int lane = threadIdx.x & 63;
  int row = blockIdx.x * 4 + wid;      // ((s*B)+b)*NH+n
  int n = row % NH;
  int sb = row / NH;
  int b = sb % B;
  int s = sb / B;
  int base = (s * B + b) * Dm + n * DH;
  float qv = b2f(q[base + lane]);
  float vv = b2f(v[base + lane]);
  float kv = b2f(k[base + lane]);
  float cq = qv > 0.0f ? qv + 1.0f : expf(qv);   // elu+1
  float ck = vv > 0.0f ? vv + 1.0f : expf(vv);
  float nr = mnorm[(size_t)(b * NH + n) * DH + lane];
  float denq = wave_sum(cq * nr);
  float denk = wave_sum(ck * nr);
  const float* mrow = mem + (size_t)(b * NH + n) * DH * DH;
  float numq = 0.0f, numk = 0.0f;
  #pragma unroll 8
  for (int kk = 0; kk < DH; kk++) {
    float mval = mrow[(size_t)kk * DH + lane];
    numq += __shfl(cq, kk, 64) * mval;
    numk += __shfl(ck, kk, 64) * mval;
  }
  float gate = 1.0f / (1.0f + expf(-0.01f));
  float content = numq / denq;
  float delta = numk / denk;
  att[base + lane] = f2b(gate * content + (1.0f - gate) * b2f(att[base + lane]));
  vd[base + lane] = f2b(kv - delta);
}

// new_mem[b,n,k,v] = mem + sum_s cK[s,k]*vd[s,v];  new_norm[b,n,k] = norm + sum_s cK[s,k]
__global__ void memupd_kernel(const bf16* __restrict__ v, const bf16* __restrict__ vd,
                              const float* __restrict__ mem, const float* __restrict__ mnorm,
                              float* __restrict__ out_mem, float* __restrict__ out_norm) {
  int b = blockIdx.x / NH, n = blockIdx.x % NH;
  int t = threadIdx.x;        // 256
  int k = t >> 2;             // 0..63
  int v0 = (t & 3) * 16;      // 0,16,32,48
  __shared__ float ckl[8][DH];
  __shared__ float vdl[8][DH];
  float acc[16];
  #pragma unroll
  for (int j = 0; j < 16; j++) acc[j] = 0.0f;
  float nsum = 0.0f;
  for (int s0 = 0; s0 < S; s0 += 8) {
    #pragma unroll
    for (int i2 = 0; i2 < 2; i2++) {
      int idx = t + i2 * 256;        // 0..511
      int sp = idx >> 6, dd = idx & 63;
      int g = ((s0 + sp) * B + b) * Dm + n * DH + dd;
      float vv = b2f(v[g]);
      ckl[sp][dd] = vv > 0.0f ? vv + 1.0f : expf(vv);
      vdl[sp][dd] = b2f(vd[g]);
    }
    __syncthreads();
    #pragma unroll
    for (int sp = 0; sp < 8; sp++) {
      float c = ckl[sp][k];
      if ((t & 3) == 0) nsum += c;
      #pragma unroll
      for (int j = 0; j < 16; j++) acc[j] += c * vdl[sp][v0 + j];
    }
    __syncthreads();
  }
  const float* mrow = mem + (size_t)(b * NH + n) * DH * DH;
  float* orow = out_mem + (size_t)(b * NH + n) * DH * DH;
  #pragma unroll
  for (int j = 0; j < 16; j++) {
    int idx = k * DH + v0 + j;
    orow[idx] = mrow[idx] + acc[j];
  }
  if ((t & 3) == 0) {
    int idx = (b * NH + n) * DH + k;
    out_norm[idx] = mnorm[idx] + nsum;
  }
}

// out = layer_norm(x + y, g, b); one block per row of 768
template <typename TX, typename TY, typename TO>
__global__ void addln_kernel(const TX* __restrict__ x, const TY* __restrict__ y,
                             const float* __restrict__ g, const float* __restrict__ bb,
                             TO* __restrict__ out) {
  int row = blockIdx.x;
  int t = threadIdx.x;      // 256
  float vals[3];
  float sum = 0.0f, sq = 0.0f;
  #pragma unroll
  for (int i = 0; i < 3; i++) {
    size_t idx = (size_t)row * Dm + t + i * 256;
    float vv = ldv(x, idx) + ldv(y, idx);
    vals[i] = vv;
    sum += vv;
    sq += vv * vv;
  }
  sum = wave_sum(sum);
  sq = wave_sum(sq);
  __shared__ float s1[4], s2[4];
  int w = t >> 6, lane = t & 63;
  if (lane == 0) { s1[w] = sum; s2[w] = sq; }
  __syncthreads();
  if (t == 0) {
    s1[0] = s1[0] + s1[1] + s1[2] + s1[3];
    s2[0] = s2[0] + s2[1] + s2[2] + s2[3];
  }
  __syncthreads();
  sum = s1[0]; sq = s2[0];
  float mu = sum / 768.0f;
  float var = sq / 768.0f - mu * mu;
  float rs = rsqrtf(var + 1e-5f);
  #pragma unroll
  for (int i = 0; i < 3; i++) {
    int d = t + i * 256;
    stv(out, (size_t)row * Dm + d, (vals[i] - mu) * rs * g[d] + bb[d]);
  }
}

extern "C" void kernel_launch(void* const* d_in, const int* in_sizes, int n_in,
                              void* d_out, int out_size, void* d_ws, size_t ws_size,
                              hipStream_t stream) {
  (void)in_sizes; (void)n_in; (void)out_size; (void)ws_size;
  const int*   inp   = (const int*)d_in[0];
  const float* wemb  = (const float*)d_in[1];
  const float* Wq    = (const float*)d_in[2];
  const float* Wkv   = (const float*)d_in[3];
  const float* Wo    = (const float*)d_in[4];
  const float* ln1g  = (const float*)d_in[5];
  const float* ln1b  = (const float*)d_in[6];
  const float* fW1   = (const float*)d_in[7];
  const float* fb1   = (const float*)d_in[8];
  const float* fW2   = (const float*)d_in[9];
  const float* fb2   = (const float*)d_in[10];
  const float* ln2g  = (const float*)d_in[11];
  const float* ln2b  = (const float*)d_in[12];
  const float* mem   = (const float*)d_in[13];
  const float* mnorm = (const float*)d_in[14];

  const size_t SBD = (size_t)S * B * Dm;   // 3,145,728

  bf16* ws   = (bf16*)d_ws;
  bf16* q    = ws;              // slot 0
  bf16* kbuf = ws + SBD;        // slot 1
  bf16* vbuf = ws + 2 * SBD;    // slot 2
  bf16* vd   = ws + 3 * SBD;    // slot 3
  bf16* att  = ws + 4 * SBD;    // slot 4
  bf16* out1 = ws + 5 * SBD;    // slot 5
  bf16* ffm  = q;               // 4*SBD: aliases slots 0-3 (dead by FF1)
  bf16* tmp  = q;               // Wo-GEMM out (q dead after meminfer)
  bf16* ff2o = att;             // FF2 out (att dead after Wo-GEMM)

  float* h    = (float*)d_out;  // residual stream lives in d_out (fp32)
  float* outm = h + SBD;
  float* outn = outm + (size_t)NL * B * NH * DH * DH;

  dim3 b256(256);
  embed_kernel<<<dim3((S * B * Dm + 255) / 256), b256, 0, stream>>>(inp, wemb, h);

  for (int l = 0; l < NL; l++) {
    const float* Wq_l  = Wq + (size_t)l * Dm * Dm;
    const float* Wk_l  = Wkv + (size_t)l * 2 * Dm * Dm;      // rows 0..D-1  -> k
    const float* Wv_l  = Wk_l + (size_t)Dm * Dm;             // rows D..2D-1 -> v
    const float* Wo_l  = Wo + (size_t)l * Dm * Dm;
    const float* mem_l = mem + (size_t)l * B * NH * DH * DH;
    const float* mn_l  = mnorm + (size_t)l * B * NH * DH;

    gemm_mfma<<<dim3(Dm / 128, 32), b256, 0, stream>>>(h, Wq_l, (const float*)nullptr, q, Dm, Dm, 0);
    gemm_mfma<<<dim3(Dm / 128, 32), b256, 0, stream>>>(h, Wk_l, (const float*)nullptr, kbuf, Dm, Dm, 0);
    gemm_mfma<<<dim3(Dm / 128, 32), b256, 0, stream>>>(h, Wv_l, (const float*)nullptr, vbuf, Dm, Dm, 0);

    attn_flash<<<dim3(S / 64, B * NH), b256, 0, stream>>>(q, kbuf, vbuf, att);
    meminfer_kernel<<<dim3(S * B * NH / 4), b256, 0, stream>>>(q, kbuf, vbuf, mem_l, mn_l,
                                                               att, vd);
    memupd_kernel<<<dim3(B * NH), b256, 0, stream>>>(vbuf, vd, mem_l, mn_l,
        outm + (size_t)l * B * NH * DH * DH, outn + (size_t)l * B * NH * DH);

    gemm_mfma<<<dim3(Dm / 128, 32), b256, 0, stream>>>(att, Wo_l, (const float*)nullptr, tmp, Dm, Dm, 0);
    addln_kernel<<<dim3(S * B), b256, 0, stream>>>(h, tmp, ln1g + l * Dm, ln1b + l * Dm, out1);

    gemm_mfma<<<dim3(DI / 128, 32), b256, 0, stream>>>(out1, fW1 + (size_t)l * DI * Dm,
                                                       fb1 + l * DI, ffm, DI, Dm, 1);
    gemm_mfma<<<dim3(Dm / 128, 32), b256, 0, stream>>>(ffm, fW2 + (size_t)l * Dm * DI,
                                                       fb2 + l * Dm, ff2o, Dm, DI, 0);
    addln_kernel<<<dim3(S * B), b256, 0, stream>>>(out1, ff2o, ln2g + l * Dm, ln2b + l * Dm, h);
  }
}